// Round 5
// baseline (123.618 us; speedup 1.0000x reference)
//
#include <hip/hip_runtime.h>

// Real solid spherical harmonics up to l=6 (49 outputs) for N points.
// v4: ns_lms folded into the constexpr coefficient table (no global loads
// except xyz), single compute phase, BLOCK=128 (25 KiB LDS -> 6 blocks/CU),
// one barrier, coalesced nontemporal f4 stores at kernel end.

namespace {

constexpr int MAXL   = 6;
constexpr int NOUT   = (MAXL + 1) * (MAXL + 1);  // 49
constexpr int NT_MAX = 256;

typedef float f4 __attribute__((ext_vector_type(4)));

struct Tab {
    int   px[NT_MAX];
    int   py[NT_MAX];
    int   pz[NT_MAX];
    float clm[NT_MAX];   // clm * ns folded
    int   dst[NT_MAX];
    bool  last[NT_MAX];  // true on the final term of each (l,m) group
    int   cnt;
};

constexpr long long comb(int n, int k) {
    if (k < 0 || k > n) return 0;
    long long r = 1;
    for (int i = 0; i < k; ++i) r = r * (n - i) / (i + 1);  // exact at each step
    return r;
}

constexpr double dfact(int n) {  // n <= 12: exact in double
    double r = 1.0;
    for (int i = 2; i <= n; ++i) r *= (double)i;
    return r;
}

constexpr double csqrt(double x) {  // Newton, converges to 0.5 ulp
    double g = x > 1.0 ? x : 1.0;
    for (int i = 0; i < 64; ++i) g = 0.5 * (g + x / g);
    return g;
}

constexpr Tab build_tab() {
    Tab tb{};
    int k = 0;
    for (int l = 0; l <= MAXL; ++l) {
        for (int m = -l; m <= l; ++m) {
            const int am  = (m < 0) ? -m : m;
            // ns_lm = 1/(2^|m| l!) * sqrt(2 (l+|m|)! (l-|m|)! / (m==0 ? 2 : 1))
            double ns = 1.0;
            for (int i = 0; i < am; ++i) ns *= 0.5;
            ns = ns / dfact(l)
               * csqrt(2.0 * dfact(l + am) * dfact(l - am) / (m == 0 ? 2.0 : 1.0));
            const int v2s = (m < 0) ? 1 : 0;
            const int v2e = 2 * ((m < 0) ? (am - 1) / 2 : am / 2) + v2s;
            for (int t = 0; t <= (l - am) / 2; ++t) {
                for (int u = 0; u <= t; ++u) {
                    for (int v2 = v2s; v2 <= v2e; v2 += 2) {
                        const int parity = (t + (v2 - v2s) / 2) % 2;
                        double c = parity ? -1.0 : 1.0;
                        for (int i = 0; i < t; ++i) c *= 0.25;
                        c *= (double)comb(l, t);
                        c *= (double)((am + t <= l - t) ? comb(l - t, am + t) : 0);
                        c *= (double)comb(t, u);
                        c *= (double)((v2 <= am) ? comb(am, v2) : 0);
                        tb.dst[k] = l * (l + 1) + m;
                        tb.px[k]  = 2 * t + am - 2 * u - v2;
                        tb.py[k]  = 2 * u + v2;
                        tb.pz[k]  = l - 2 * t - am;
                        tb.clm[k] = (float)(c * ns);
                        tb.last[k] = false;
                        ++k;
                    }
                }
            }
            tb.last[k - 1] = true;  // every (l,m) has >=1 term
        }
    }
    tb.cnt = k;
    return tb;
}

constexpr Tab TB = build_tab();
static_assert(TB.cnt == 188, "expected 188 terms for max_l=6");

constexpr int BLOCK = 128;
constexpr int SLAB4 = BLOCK * NOUT / 4;  // 1568 f4 per block

}  // namespace

__global__ __launch_bounds__(BLOCK) void rsh_kernel(const float* __restrict__ xyz,
                                                    float* __restrict__ out,
                                                    int N) {
    __shared__ float sm[BLOCK * NOUT];  // 25088 B -> 6 blocks/CU by LDS

    const int tid = threadIdx.x;
    const int blk = blockIdx.x;
    const int i   = blk * BLOCK + tid;

    float x = 0.f, y = 0.f, z = 0.f;
    if (i < N) {
        const float* p = xyz + (long long)i * 3;
        x = p[0]; y = p[1]; z = p[2];
    }

    // power tables (statically indexed after full unroll -> registers)
    float xp[MAXL + 1], yp[MAXL + 1], zp[MAXL + 1];
    xp[0] = yp[0] = zp[0] = 1.f;
#pragma unroll
    for (int p = 1; p <= MAXL; ++p) {
        xp[p] = xp[p - 1] * x;
        yp[p] = yp[p - 1] * y;
        zp[p] = zp[p - 1] * z;
    }

    // streaming accumulator: table is dst-ordered; write each finished (l,m)
    // to LDS row tid (stride 49 dwords: odd -> bank-conflict-free).
    float acc = 0.f;
#pragma unroll
    for (int k = 0; k < TB.cnt; ++k) {
        acc = fmaf(TB.clm[k], xp[TB.px[k]] * yp[TB.py[k]] * zp[TB.pz[k]], acc);
        if (TB.last[k]) {  // compile-time constant after unroll
            sm[tid * NOUT + TB.dst[k]] = acc;
            acc = 0.f;
        }
    }

    __syncthreads();

    // cooperative, coalesced nontemporal f4 store of the block's output slab
    const f4* s4 = (const f4*)sm;
    f4* o4 = (f4*)out;
    const int base4 = blk * SLAB4;
    const int lim4  = (N * NOUT) >> 2;  // 6.125M, fits int
    const int remF  = (N * NOUT) & 3;
#pragma unroll
    for (int it = 0; it < SLAB4 / BLOCK + 1; ++it) {  // 12 full + 1 partial-range
        const int f = it * BLOCK + tid;
        if (f < SLAB4) {
            const int g = base4 + f;
            if (g < lim4) {
                __builtin_nontemporal_store(s4[f], o4 + g);
            } else if (g == lim4 && remF) {
#pragma unroll
                for (int t = 0; t < 3; ++t)
                    if (t < remF) out[(long long)g * 4 + t] = sm[f * 4 + t];
            }
        }
    }
}

extern "C" void kernel_launch(void* const* d_in, const int* in_sizes, int n_in,
                              void* d_out, int out_size, void* d_ws, size_t ws_size,
                              hipStream_t stream) {
    const float* xyz = (const float*)d_in[0];
    float* out = (float*)d_out;

    const int N = in_sizes[0] / 3;
    const int grid = (N + BLOCK - 1) / BLOCK;
    rsh_kernel<<<grid, BLOCK, 0, stream>>>(xyz, out, N);
}